// Round 3
// baseline (369.770 us; speedup 1.0000x reference)
//
#include <hip/hip_runtime.h>
#include <hip/hip_bf16.h>
#include <math.h>

// Problem constants (from reference setup_inputs)
#define ND 4      // batch n
#define CL 1024   // sequence length c
#define DD 768    // hidden d
#define HH 12     // heads h
#define EE 32     // entities E
#define MMEN 4    // mentions M
#define PP 256    // pairs P
#define EMBD 768  // EMB
#define KBL 12    // K = EMB/BLOCK
#define OUTD 97   // output classes
#define RTOT (ND*PP)  // 1024 rows
#define NSPLIT 48     // bilinear split-K factor (each sp covers 1024 K-elems)

typedef unsigned short u16;
typedef __attribute__((ext_vector_type(8))) short short8;
typedef __attribute__((ext_vector_type(8))) _Float16 half8;
typedef __attribute__((ext_vector_type(4))) float f32x4;

static __device__ inline float bf16u_to_f(unsigned v){
  union { unsigned u; float f; } c; c.u = v << 16; return c.f;
}
static __device__ inline unsigned f_to_bf16u(float f){
  union { float f; unsigned u; } c; c.f = f;
  return (c.u + 0x7fffu + ((c.u >> 16) & 1u)) >> 16;
}
static __device__ inline u16 f_to_f16u(float f){
  _Float16 h = (_Float16)f;
  union { _Float16 h; u16 u; } c; c.h = h; return c.u;
}

#define GLOAD_LDS16(gp, lp) __builtin_amdgcn_global_load_lds( \
    (const __attribute__((address_space(1))) unsigned*)(gp), \
    (__attribute__((address_space(3))) unsigned*)(lp), 16, 0, 0)

// ---------------------------------------------------------------
// 1. FUSED preprocessing: all input-only transforms in ONE launch.
//    blockIdx.x ranges:
//      [0,384)        ent_emb   (+ zero S)
//      [384,1152)     ent_att   (+ init logits = bias)
//      [1152,4224)    seq transpose  (24 x 32 x 4)
//      [4224,6528)    W_head/W_tail transpose (24 x 48 x 2)
//      [6528,8064)    Wt2 (chunked/padded f16 image of W_bil)
// ---------------------------------------------------------------
__global__ __launch_bounds__(256) void k_preproc(
    const float* __restrict__ seq, const float* __restrict__ attn,
    const int* __restrict__ mpos,
    const float* __restrict__ W_head, const float* __restrict__ W_tail,
    const float* __restrict__ W_bil, const float* __restrict__ b_bil,
    u16* __restrict__ ent_emb_bf, u16* __restrict__ ent_att_bf,
    u16* __restrict__ seq_t_bf, u16* __restrict__ Wh_t, u16* __restrict__ Wt_t,
    u16* __restrict__ Wt2, float* __restrict__ S, float* __restrict__ logits)
{
  __shared__ float t[32][33];                  // transpose staging
  __shared__ __align__(16) u16 lds2[4480];     // wt2 staging
  const int bid = blockIdx.x;
  const int tid = threadIdx.x;

  if (bid < 384) {
    // ---- ent_emb: logsumexp over mentions; also zero S[1024]
    int idx = bid*256 + tid;                   // exactly ND*EE*DD = 98304
    if (idx < RTOT) S[idx] = 0.f;
    int dd = idx % DD;
    int e  = (idx / DD) % EE;
    int i  = idx / (DD*EE);
    const int* mp = mpos + (i*EE + e)*MMEN;
    float v[MMEN];
    float mx = -1e30f;
    #pragma unroll
    for (int m=0;m<MMEN;m++){
      v[m] = seq[(i*CL + mp[m])*DD + dd];
      mx = fmaxf(mx, v[m]);
    }
    float s = 0.f;
    #pragma unroll
    for (int m=0;m<MMEN;m++) s += expf(v[m]-mx);
    ent_emb_bf[idx] = (u16)f_to_bf16u(mx + logf(s));
  }
  else if (bid < 1152) {
    // ---- ent_att: mean over mentions of attention rows, bf16 packed
    int idx = (bid-384)*256 + tid;             // exactly ND*EE*HH*(CL/8)
    // piggyback: init logits = bias (bilinear accumulates atomically)
    if (idx < RTOT*OUTD) logits[idx] = b_bil[idx % OUTD];
    int j8   = idx % (CL/8);
    int head = (idx / (CL/8)) % HH;
    int e    = (idx / (CL/8*HH)) % EE;
    int i    = idx / (CL/8*HH*EE);
    const int* mp = mpos + (i*EE + e)*MMEN;
    float acc[8] = {};
    #pragma unroll
    for (int m=0;m<MMEN;m++){
      const float4* p = (const float4*)(attn +
          ((size_t)(i*HH + head)*CL + mp[m])*CL + j8*8);
      float4 a = p[0], b = p[1];
      acc[0]+=a.x; acc[1]+=a.y; acc[2]+=a.z; acc[3]+=a.w;
      acc[4]+=b.x; acc[5]+=b.y; acc[6]+=b.z; acc[7]+=b.w;
    }
    unsigned o[4];
    #pragma unroll
    for (int q=0;q<4;q++){
      unsigned lo = f_to_bf16u(acc[2*q]   * (1.f/MMEN));
      unsigned hi = f_to_bf16u(acc[2*q+1] * (1.f/MMEN));
      o[q] = lo | (hi<<16);
    }
    ((uint4*)ent_att_bf)[idx] = make_uint4(o[0],o[1],o[2],o[3]);
  }
  else if (bid < 4224) {
    // ---- seq transpose: seq_t_bf[z][C][R] = bf16(seq[z][R][C]), R=CL, C=DD
    int l = bid - 1152;
    int bx = l % 24;             // DD/32
    int by = (l / 24) % 32;      // CL/32
    int bz = l / 768;
    const int R = CL, C = DD;
    const float* src = seq + (size_t)bz*R*C;
    u16* dst = seq_t_bf + (size_t)bz*R*C;
    int tx = tid & 31, ty = tid >> 5;
    int c0 = bx*32, r0 = by*32;
    #pragma unroll
    for (int q=0;q<4;q++)
      t[ty+8*q][tx] = src[(size_t)(r0+ty+8*q)*C + c0+tx];
    __syncthreads();
    #pragma unroll
    for (int q=0;q<4;q++)
      dst[(size_t)(c0+ty+8*q)*R + r0+tx] = (u16)f_to_bf16u(t[tx][ty+8*q]);
  }
  else if (bid < 6528) {
    // ---- W_head / W_tail transpose: R=1536, C=768
    int l = bid - 4224;
    int bx = l % 24;             // DD/32
    int by = (l / 24) % 48;      // 1536/32
    int bz = l / 1152;
    const int R = 1536, C = DD;
    const float* src = bz ? W_tail : W_head;
    u16* dst         = bz ? Wt_t   : Wh_t;
    int tx = tid & 31, ty = tid >> 5;
    int c0 = bx*32, r0 = by*32;
    #pragma unroll
    for (int q=0;q<4;q++)
      t[ty+8*q][tx] = src[(size_t)(r0+ty+8*q)*C + c0+tx];
    __syncthreads();
    #pragma unroll
    for (int q=0;q<4;q++)
      dst[(size_t)(c0+ty+8*q)*R + r0+tx] = (u16)f_to_bf16u(t[tx][ty+8*q]);
  }
  else {
    // ---- Wt2: chunked, transposed, padded f16 image of W_bil
    int cc = bid - 6528;         // 0..1535
    for (int u=tid; u<4480; u+=256) lds2[u] = 0;
    __syncthreads();
    for (int u=tid; u<112*32; u+=256){
      int kk = u / 112, n = u % 112;
      if (n < OUTD)
        lds2[n*40 + kk] = f_to_f16u(W_bil[(size_t)(cc*32 + kk)*OUTD + n]);
    }
    __syncthreads();
    uint4* dst = (uint4*)(Wt2 + (size_t)cc*4480);
    const uint4* src = (const uint4*)lds2;
    for (int v=tid; v<560; v+=256) dst[v] = src[v];
  }
}

// ---------------------------------------------------------------
// 3. u_ht[p,j] = mean_head ha*ta (unnormalized bf16) + row sums S[p].
// ---------------------------------------------------------------
__global__ __launch_bounds__(256) void k_ht_att(const u16* __restrict__ ent_att_bf,
    const int* __restrict__ hts, u16* __restrict__ u_ht_bf, float* __restrict__ S)
{
  const int j0  = blockIdx.x*64;
  const int pb  = blockIdx.y*64;
  const int doc = blockIdx.z;
  const int tid = threadIdx.x;
  const int p_local = tid >> 2, quad = tid & 3;
  const int grow = doc*PP + pb + p_local;
  const int he = hts[grow*2+0], te = hts[grow*2+1];
  const u16* ha = ent_att_bf + ((size_t)(doc*EE + he)*HH)*CL;
  const u16* ta = ent_att_bf + ((size_t)(doc*EE + te)*HH)*CL;
  const int jj = j0 + quad*16;

  float acc[16] = {};
  #pragma unroll
  for (int h=0; h<HH; h++){
    const uint4* pa = (const uint4*)(ha + h*CL + jj);
    const uint4* pb4 = (const uint4*)(ta + h*CL + jj);
    uint4 a0 = pa[0], a1 = pa[1];
    uint4 b0 = pb4[0], b1 = pb4[1];
    unsigned ua[8] = {a0.x,a0.y,a0.z,a0.w,a1.x,a1.y,a1.z,a1.w};
    unsigned ub[8] = {b0.x,b0.y,b0.z,b0.w,b1.x,b1.y,b1.z,b1.w};
    #pragma unroll
    for (int q=0;q<8;q++){
      acc[2*q]   += bf16u_to_f(ua[q]&0xffffu) * bf16u_to_f(ub[q]&0xffffu);
      acc[2*q+1] += bf16u_to_f(ua[q]>>16)     * bf16u_to_f(ub[q]>>16);
    }
  }
  float sum = 0.f;
  unsigned o[8];
  #pragma unroll
  for (int q=0;q<8;q++){
    float v0 = acc[2*q]   * (1.f/HH);
    float v1 = acc[2*q+1] * (1.f/HH);
    sum += v0 + v1;
    o[q] = f_to_bf16u(v0) | (f_to_bf16u(v1)<<16);
  }
  uint4* dst = (uint4*)(u_ht_bf + (size_t)grow*CL + jj);
  dst[0] = make_uint4(o[0],o[1],o[2],o[3]);
  dst[1] = make_uint4(o[4],o[5],o[6],o[7]);
  sum += __shfl_xor(sum, 1, 64);
  sum += __shfl_xor(sum, 2, 64);
  if (quad == 0) atomicAdd(&S[grow], sum);
}

// ---------------------------------------------------------------
// 4. rs_bf = bf16( (1/S_row) * (u_ht @ seq) ) via MFMA.
//    BM=64 BN=64 BK=64; grid (4,12,4) = 192 blocks.
// ---------------------------------------------------------------
__global__ __launch_bounds__(256) void k_gemm_rs_mfma(
    const u16* __restrict__ u_ht_bf, const u16* __restrict__ seq_t_bf,
    const float* __restrict__ S, u16* __restrict__ rs_bf)
{
  const int rt = blockIdx.x, ct = blockIdx.y, doc = blockIdx.z;
  const u16* A  = u_ht_bf + (size_t)doc*PP*CL;
  const u16* Bt = seq_t_bf + (size_t)doc*DD*CL;
  const int row0 = rt*64, col0 = ct*64;
  __shared__ __align__(16) u16 As[64*64];
  __shared__ __align__(16) u16 Bs[64*64];
  const int tid = threadIdx.x, lane = tid & 63, wave = tid >> 6;
  const int m = lane & 15, j8 = lane >> 4;
  const int srow8 = lane >> 3, sc8 = lane & 7;
  f32x4 acc[4];
  #pragma unroll
  for (int b=0;b<4;b++) acc[b] = (f32x4){0.f,0.f,0.f,0.f};

  for (int k0 = 0; k0 < CL; k0 += 64){
    __syncthreads();
    #pragma unroll
    for (int ii=0; ii<2; ii++){
      int row = ii*32 + wave*8 + srow8;
      int gc = sc8 ^ (row & 7);
      const u16* gpA = A + (size_t)(row0+row)*CL + k0 + gc*8;
      GLOAD_LDS16(gpA, &As[(ii*32 + wave*8)*64]);
      const u16* gpB = Bt + (size_t)(col0+row)*CL + k0 + gc*8;
      GLOAD_LDS16(gpB, &Bs[(ii*32 + wave*8)*64]);
    }
    __syncthreads();
    #pragma unroll
    for (int h=0; h<2; h++){
      short8 af, bf[4];
      {
        int r = wave*16 + m;
        int c = (h*4 + j8) ^ (r & 7);
        af = *(const short8*)&As[r*64 + c*8];
      }
      #pragma unroll
      for (int nt=0; nt<4; nt++){
        int n = nt*16 + m;
        int c = (h*4 + j8) ^ (n & 7);
        bf[nt] = *(const short8*)&Bs[n*64 + c*8];
      }
      #pragma unroll
      for (int nt=0; nt<4; nt++)
        acc[nt] = __builtin_amdgcn_mfma_f32_16x16x32_bf16(af, bf[nt], acc[nt], 0,0,0);
    }
  }

  // hoisted 1/S scales (independent of nt)
  float sc[4];
  #pragma unroll
  for (int reg=0; reg<4; reg++){
    int rowg = doc*PP + row0 + wave*16 + j8*4 + reg;
    sc[reg] = 1.f / (S[rowg] + 1e-30f);
  }
  #pragma unroll
  for (int nt=0; nt<4; nt++){
    int colg = col0 + nt*16 + m;
    #pragma unroll
    for (int reg=0; reg<4; reg++){
      int rowg = doc*PP + row0 + wave*16 + j8*4 + reg;
      rs_bf[(size_t)rowg*DD + colg] = (u16)f_to_bf16u(acc[nt][reg] * sc[reg]);
    }
  }
}

// ---------------------------------------------------------------
// 5. hs2h = f16(tanh([ent_emb|rs] @ W_head + b_head)); ts2h analogous.
// ---------------------------------------------------------------
__global__ __launch_bounds__(256) void k_gemm_ht_mfma(
    const u16* __restrict__ ent_emb_bf, const u16* __restrict__ rs_bf,
    const int* __restrict__ hts,
    const u16* __restrict__ Wht, const u16* __restrict__ Wtt,
    const float* __restrict__ b_head, const float* __restrict__ b_tail,
    u16* __restrict__ hs2h, u16* __restrict__ ts2h)
{
  const int rt = blockIdx.x, ct = blockIdx.y, z = blockIdx.z;
  const u16* Bt   = z ? Wtt : Wht;
  const float* bias = z ? b_tail : b_head;
  u16* C          = z ? ts2h : hs2h;
  const int row0 = rt*128, col0 = ct*64;
  __shared__ __align__(16) u16 As[128*64];
  __shared__ __align__(16) u16 Bs[64*64];
  const int tid = threadIdx.x, lane = tid & 63, wave = tid >> 6;
  const int m = lane & 15, j8 = lane >> 4;
  const int srow8 = lane >> 3, sc8 = lane & 7;

  const u16* gEnt[4]; const u16* gRs[4]; int gcA[4];
  #pragma unroll
  for (int ii=0; ii<4; ii++){
    int row  = ii*32 + wave*8 + srow8;
    int grow = row0 + row;
    int ent  = hts[grow*2 + z];
    gEnt[ii] = ent_emb_bf + ((size_t)((grow>>8)*EE + ent))*DD;
    gRs[ii]  = rs_bf + (size_t)grow*DD;
    gcA[ii]  = (sc8 ^ (row & 7)) * 8;
  }

  f32x4 acc[2][4];
  #pragma unroll
  for (int a=0;a<2;a++)
    #pragma unroll
    for (int b=0;b<4;b++) acc[a][b] = (f32x4){0.f,0.f,0.f,0.f};

  for (int k0 = 0; k0 < 1536; k0 += 64){
    __syncthreads();
    #pragma unroll
    for (int ii=0; ii<4; ii++){
      const u16* gp = (k0 < DD) ? (gEnt[ii] + k0 + gcA[ii])
                                : (gRs[ii] + (k0-DD) + gcA[ii]);
      GLOAD_LDS16(gp, &As[(ii*32 + wave*8)*64]);
    }
    #pragma unroll
    for (int ii=0; ii<2; ii++){
      int row = ii*32 + wave*8 + srow8;
      int gc = sc8 ^ (row & 7);
      const u16* gp = Bt + (size_t)(col0+row)*1536 + k0 + gc*8;
      GLOAD_LDS16(gp, &Bs[(ii*32 + wave*8)*64]);
    }
    __syncthreads();
    #pragma unroll
    for (int h=0; h<2; h++){
      short8 af[2], bf[4];
      #pragma unroll
      for (int mf=0; mf<2; mf++){
        int r = wave*32 + mf*16 + m;
        int c = (h*4 + j8) ^ (r & 7);
        af[mf] = *(const short8*)&As[r*64 + c*8];
      }
      #pragma unroll
      for (int nt=0; nt<4; nt++){
        int n = nt*16 + m;
        int c = (h*4 + j8) ^ (n & 7);
        bf[nt] = *(const short8*)&Bs[n*64 + c*8];
      }
      #pragma unroll
      for (int mf=0; mf<2; mf++)
        #pragma unroll
        for (int nt=0; nt<4; nt++)
          acc[mf][nt] = __builtin_amdgcn_mfma_f32_16x16x32_bf16(af[mf], bf[nt], acc[mf][nt], 0,0,0);
    }
  }

  #pragma unroll
  for (int mf=0; mf<2; mf++){
    #pragma unroll
    for (int nt=0; nt<4; nt++){
      int colg = col0 + nt*16 + m;
      float bv = bias[colg];
      #pragma unroll
      for (int reg=0; reg<4; reg++){
        int rowg = row0 + wave*32 + mf*16 + j8*4 + reg;
        C[(size_t)rowg*DD + colg] = f_to_f16u(tanhf(acc[mf][nt][reg] + bv));
      }
    }
  }
}

// ---------------------------------------------------------------
// 7. bilinear via f16 MFMA 16x16x32; A-frag = pk_mul(b1 splat, b2).
//    NSPLIT=48 (384 blocks), 4-deep Ws staging (16 barriers/block),
//    atomic-add epilogue directly into logits (pre-inited with bias).
// ---------------------------------------------------------------
__global__ __launch_bounds__(256) void k_bilinear(
    const u16* __restrict__ hs2h, const u16* __restrict__ ts2h,
    const u16* __restrict__ Wt2, float* __restrict__ logits)
{
  const int rt = blockIdx.x;          // 0..7   (128 rows each)
  const int sp = blockIdx.y;          // 0..47  (K range [sp*1024, +1024))
  const int kb = sp >> 2;             // 0..11
  const int i0 = (sp & 3) * 16;       // i base within this kb
  const int row0 = rt * 128;

  __shared__ __align__(16) u16 b1s[128][24];   // 6144 B
  __shared__ __align__(16) u16 b2s[128][72];   // 18432 B
  __shared__ __align__(16) u16 Ws[4][4480];    // 35840 B (4 c-tiles)

  const int tid = threadIdx.x;
  const int lane = tid & 63, wave = tid >> 6;
  const int m = lane & 15, j8 = lane >> 4;

  // stage b1 (16 f16/row) and b2 (64 f16/row) via uint4 copies
  {
    int r = tid >> 1, half = tid & 1;
    uint4 v = *(const uint4*)&hs2h[(size_t)(row0+r)*EMBD + kb*64 + i0 + half*8];
    *(uint4*)&b1s[r][half*8] = v;
  }
  #pragma unroll
  for (int q=0;q<4;q++){
    int u = tid + q*256;
    int r = u >> 3, seg = u & 7;
    uint4 v = *(const uint4*)&ts2h[(size_t)(row0+r)*EMBD + kb*64 + seg*8];
    *(uint4*)&b2s[r][seg*8] = v;
  }

  const uint4* gsrc = (const uint4*)(Wt2 + (size_t)(sp*32)*4480);
  uint4* ws4 = (uint4*)Ws;
  // prefetch super 0: 2240 uint4 (4 c-tiles of 560)
  uint4 pf0,pf1,pf2,pf3,pf4,pf5,pf6,pf7,pf8;
  pf0 = gsrc[tid];        pf1 = gsrc[tid+256];  pf2 = gsrc[tid+512];
  pf3 = gsrc[tid+768];    pf4 = gsrc[tid+1024]; pf5 = gsrc[tid+1280];
  pf6 = gsrc[tid+1536];   pf7 = gsrc[tid+1792];
  if (tid < 192) pf8 = gsrc[tid+2048];

  f32x4 acc[2][7];
  #pragma unroll
  for (int f=0;f<2;f++)
    #pragma unroll
    for (int nt=0;nt<7;nt++) acc[f][nt] = (f32x4){0.f,0.f,0.f,0.f};

  for (int s=0; s<8; s++){
    __syncthreads();
    ws4[tid]      = pf0; ws4[tid+256]  = pf1; ws4[tid+512]  = pf2;
    ws4[tid+768]  = pf3; ws4[tid+1024] = pf4; ws4[tid+1280] = pf5;
    ws4[tid+1536] = pf6; ws4[tid+1792] = pf7;
    if (tid < 192) ws4[tid+2048] = pf8;
    if (s+1 < 8){
      size_t b = (size_t)(s+1)*2240;
      pf0 = gsrc[b+tid];      pf1 = gsrc[b+tid+256];  pf2 = gsrc[b+tid+512];
      pf3 = gsrc[b+tid+768];  pf4 = gsrc[b+tid+1024]; pf5 = gsrc[b+tid+1280];
      pf6 = gsrc[b+tid+1536]; pf7 = gsrc[b+tid+1792];
      if (tid < 192) pf8 = gsrc[b+tid+2048];
    }
    __syncthreads();

    #pragma unroll
    for (int qq=0; qq<4; qq++){
      const int c = s*4 + qq;          // 0..31
      const int i_rel = c >> 1;        // 0..15
      const int j0 = (c & 1) * 32;

      half8 bfr[7];
      #pragma unroll
      for (int nt=0;nt<7;nt++)
        bfr[nt] = *(const half8*)&Ws[qq][(nt*16 + m)*40 + j8*8];

      #pragma unroll
      for (int f=0;f<2;f++){
        int r = wave*32 + f*16 + m;
        _Float16 sv1 = *(const _Float16*)&b1s[r][i_rel];
        half8 sv = {sv1,sv1,sv1,sv1,sv1,sv1,sv1,sv1};
        half8 b2v = *(const half8*)&b2s[r][j0 + j8*8];
        half8 af = sv * b2v;             // v_pk_mul_f16 x4
        #pragma unroll
        for (int nt=0;nt<7;nt++)
          acc[f][nt] = __builtin_amdgcn_mfma_f32_16x16x32_f16(af, bfr[nt], acc[f][nt], 0, 0, 0);
      }
    }
  }

  // epilogue: atomic accumulate into logits (bias pre-added by k_preproc)
  #pragma unroll
  for (int f=0;f<2;f++){
    #pragma unroll
    for (int nt=0;nt<7;nt++){
      int col = nt*16 + m;
      if (col < OUTD){
        #pragma unroll
        for (int reg=0;reg<4;reg++){
          int lrow = wave*32 + f*16 + j8*4 + reg;
          atomicAdd(&logits[(size_t)(row0+lrow)*OUTD + col], acc[f][nt][reg]);
        }
      }
    }
  }
}

// ---------------------------------------------------------------
extern "C" void kernel_launch(void* const* d_in, const int* in_sizes, int n_in,
                              void* d_out, int out_size, void* d_ws, size_t ws_size,
                              hipStream_t stream)
{
  const float* seq    = (const float*)d_in[0];
  const float* attn   = (const float*)d_in[1];
  const int*   mpos   = (const int*)d_in[2];
  const int*   hts    = (const int*)d_in[3];
  const float* W_head = (const float*)d_in[4];
  const float* b_head = (const float*)d_in[5];
  const float* W_tail = (const float*)d_in[6];
  const float* b_tail = (const float*)d_in[7];
  const float* W_bil  = (const float*)d_in[8];
  const float* b_bil  = (const float*)d_in[9];
  float* logits = (float*)d_out;

  float* ws = (float*)d_ws;
  u16*   ent_emb_bf = (u16*)(ws + 0);          //  98304 u16 ->  49152 f
  float* S          = ws + 49152;              //   1024 f
  u16*   rs_bf      = (u16*)(ws + 50176);      // 786432 u16 -> 393216 f
  u16*   hs2h       = (u16*)(ws + 443392);     // 786432 u16 -> 393216 f
  u16*   ts2h       = (u16*)(ws + 836608);     // 786432 u16 -> 393216 f
  u16*   Wh_t       = (u16*)(ws + 1229824);    // 1179648 u16 -> 589824 f
  u16*   Wt_t       = (u16*)(ws + 1819648);    // 1179648 u16 -> 589824 f
  u16*   ent_att_bf = (u16*)(ws + 2409472);    // 1572864 u16 -> 786432 f
  u16*   u_ht_bf    = (u16*)(ws + 3195904);    // 1048576 u16 -> 524288 f
  u16*   seq_t_bf   = (u16*)(ws + 3720192);    // 3145728 u16 -> 1572864 f
  u16*   Wt2        = (u16*)(ws + 5293056);    // 6881280 u16 -> 3440640 f

  // one fused launch for all independent preprocessing (+ logits=bias init)
  k_preproc<<<8064, 256, 0, stream>>>(seq, attn, mpos, W_head, W_tail, W_bil,
      b_bil, ent_emb_bf, ent_att_bf, seq_t_bf, Wh_t, Wt_t, Wt2, S, logits);
  k_ht_att<<<dim3(16, 4, 4), 256, 0, stream>>>(ent_att_bf, hts, u_ht_bf, S);
  k_gemm_rs_mfma<<<dim3(4, 12, 4), 256, 0, stream>>>(u_ht_bf, seq_t_bf, S, rs_bf);
  k_gemm_ht_mfma<<<dim3(8, 12, 2), 256, 0, stream>>>(ent_emb_bf, rs_bf, hts,
      Wh_t, Wt_t, b_head, b_tail, hs2h, ts2h);
  k_bilinear<<<dim3(RTOT/128, NSPLIT), 256, 0, stream>>>(hs2h, ts2h, Wt2, logits);
}

// Round 5
// 344.091 us; speedup vs baseline: 1.0746x; 1.0746x over previous
//
#include <hip/hip_runtime.h>
#include <hip/hip_bf16.h>
#include <math.h>

// Problem constants (from reference setup_inputs)
#define ND 4      // batch n
#define CL 1024   // sequence length c
#define DD 768    // hidden d
#define HH 12     // heads h
#define EE 32     // entities E
#define MMEN 4    // mentions M
#define PP 256    // pairs P
#define EMBD 768  // EMB
#define KBL 12    // K = EMB/BLOCK
#define OUTD 97   // output classes
#define RTOT (ND*PP)  // 1024 rows
#define NSPLIT 48     // bilinear split-K factor (each sp covers 1024 K-elems)

typedef unsigned short u16;
typedef __attribute__((ext_vector_type(8))) short short8;
typedef __attribute__((ext_vector_type(8))) _Float16 half8;
typedef __attribute__((ext_vector_type(4))) float f32x4;

static __device__ inline float bf16u_to_f(unsigned v){
  union { unsigned u; float f; } c; c.u = v << 16; return c.f;
}
static __device__ inline unsigned f_to_bf16u(float f){
  union { float f; unsigned u; } c; c.f = f;
  return (c.u + 0x7fffu + ((c.u >> 16) & 1u)) >> 16;
}
static __device__ inline u16 f_to_f16u(float f){
  _Float16 h = (_Float16)f;
  union { _Float16 h; u16 u; } c; c.h = h; return c.u;
}

#define GLOAD_LDS16(gp, lp) __builtin_amdgcn_global_load_lds( \
    (const __attribute__((address_space(1))) unsigned*)(gp), \
    (__attribute__((address_space(3))) unsigned*)(lp), 16, 0, 0)

// ---------------------------------------------------------------
// 1. FUSED preprocessing: all input-only transforms in ONE launch.
//    blockIdx.x ranges:
//      [0,384)        ent_emb   (+ zero S)
//      [384,1152)     ent_att
//      [1152,4224)    seq transpose  (24 x 32 x 4)
//      [4224,6528)    W_head/W_tail transpose (24 x 48 x 2)
//      [6528,8064)    Wt2 (chunked/padded f16 image of W_bil)
// ---------------------------------------------------------------
__global__ __launch_bounds__(256) void k_preproc(
    const float* __restrict__ seq, const float* __restrict__ attn,
    const int* __restrict__ mpos,
    const float* __restrict__ W_head, const float* __restrict__ W_tail,
    const float* __restrict__ W_bil,
    u16* __restrict__ ent_emb_bf, u16* __restrict__ ent_att_bf,
    u16* __restrict__ seq_t_bf, u16* __restrict__ Wh_t, u16* __restrict__ Wt_t,
    u16* __restrict__ Wt2, float* __restrict__ S)
{
  __shared__ float t[32][33];                  // transpose staging
  __shared__ __align__(16) u16 lds2[4480];     // wt2 staging
  const int bid = blockIdx.x;
  const int tid = threadIdx.x;

  if (bid < 384) {
    // ---- ent_emb: logsumexp over mentions; also zero S[1024]
    int idx = bid*256 + tid;                   // exactly ND*EE*DD = 98304
    if (idx < RTOT) S[idx] = 0.f;
    int dd = idx % DD;
    int e  = (idx / DD) % EE;
    int i  = idx / (DD*EE);
    const int* mp = mpos + (i*EE + e)*MMEN;
    float v[MMEN];
    float mx = -1e30f;
    #pragma unroll
    for (int m=0;m<MMEN;m++){
      v[m] = seq[(i*CL + mp[m])*DD + dd];
      mx = fmaxf(mx, v[m]);
    }
    float s = 0.f;
    #pragma unroll
    for (int m=0;m<MMEN;m++) s += expf(v[m]-mx);
    ent_emb_bf[idx] = (u16)f_to_bf16u(mx + logf(s));
  }
  else if (bid < 1152) {
    // ---- ent_att: mean over mentions of attention rows, bf16 packed
    int idx = (bid-384)*256 + tid;             // exactly ND*EE*HH*(CL/8)
    int j8   = idx % (CL/8);
    int head = (idx / (CL/8)) % HH;
    int e    = (idx / (CL/8*HH)) % EE;
    int i    = idx / (CL/8*HH*EE);
    const int* mp = mpos + (i*EE + e)*MMEN;
    float acc[8] = {};
    #pragma unroll
    for (int m=0;m<MMEN;m++){
      const float4* p = (const float4*)(attn +
          ((size_t)(i*HH + head)*CL + mp[m])*CL + j8*8);
      float4 a = p[0], b = p[1];
      acc[0]+=a.x; acc[1]+=a.y; acc[2]+=a.z; acc[3]+=a.w;
      acc[4]+=b.x; acc[5]+=b.y; acc[6]+=b.z; acc[7]+=b.w;
    }
    unsigned o[4];
    #pragma unroll
    for (int q=0;q<4;q++){
      unsigned lo = f_to_bf16u(acc[2*q]   * (1.f/MMEN));
      unsigned hi = f_to_bf16u(acc[2*q+1] * (1.f/MMEN));
      o[q] = lo | (hi<<16);
    }
    ((uint4*)ent_att_bf)[idx] = make_uint4(o[0],o[1],o[2],o[3]);
  }
  else if (bid < 4224) {
    // ---- seq transpose: seq_t_bf[z][C][R] = bf16(seq[z][R][C]), R=CL, C=DD
    int l = bid - 1152;
    int bx = l % 24;             // DD/32
    int by = (l / 24) % 32;      // CL/32
    int bz = l / 768;
    const int R = CL, C = DD;
    const float* src = seq + (size_t)bz*R*C;
    u16* dst = seq_t_bf + (size_t)bz*R*C;
    int tx = tid & 31, ty = tid >> 5;
    int c0 = bx*32, r0 = by*32;
    #pragma unroll
    for (int q=0;q<4;q++)
      t[ty+8*q][tx] = src[(size_t)(r0+ty+8*q)*C + c0+tx];
    __syncthreads();
    #pragma unroll
    for (int q=0;q<4;q++)
      dst[(size_t)(c0+ty+8*q)*R + r0+tx] = (u16)f_to_bf16u(t[tx][ty+8*q]);
  }
  else if (bid < 6528) {
    // ---- W_head / W_tail transpose: R=1536, C=768
    int l = bid - 4224;
    int bx = l % 24;             // DD/32
    int by = (l / 24) % 48;      // 1536/32
    int bz = l / 1152;
    const int R = 1536, C = DD;
    const float* src = bz ? W_tail : W_head;
    u16* dst         = bz ? Wt_t   : Wh_t;
    int tx = tid & 31, ty = tid >> 5;
    int c0 = bx*32, r0 = by*32;
    #pragma unroll
    for (int q=0;q<4;q++)
      t[ty+8*q][tx] = src[(size_t)(r0+ty+8*q)*C + c0+tx];
    __syncthreads();
    #pragma unroll
    for (int q=0;q<4;q++)
      dst[(size_t)(c0+ty+8*q)*R + r0+tx] = (u16)f_to_bf16u(t[tx][ty+8*q]);
  }
  else {
    // ---- Wt2: chunked, transposed, padded f16 image of W_bil
    int cc = bid - 6528;         // 0..1535
    for (int u=tid; u<4480; u+=256) lds2[u] = 0;
    __syncthreads();
    for (int u=tid; u<112*32; u+=256){
      int kk = u / 112, n = u % 112;
      if (n < OUTD)
        lds2[n*40 + kk] = f_to_f16u(W_bil[(size_t)(cc*32 + kk)*OUTD + n]);
    }
    __syncthreads();
    uint4* dst = (uint4*)(Wt2 + (size_t)cc*4480);
    const uint4* src = (const uint4*)lds2;
    for (int v=tid; v<560; v+=256) dst[v] = src[v];
  }
}

// ---------------------------------------------------------------
// 3. u_ht[p,j] = mean_head ha*ta (unnormalized bf16) + row sums S[p].
// ---------------------------------------------------------------
__global__ __launch_bounds__(256) void k_ht_att(const u16* __restrict__ ent_att_bf,
    const int* __restrict__ hts, u16* __restrict__ u_ht_bf, float* __restrict__ S)
{
  const int j0  = blockIdx.x*64;
  const int pb  = blockIdx.y*64;
  const int doc = blockIdx.z;
  const int tid = threadIdx.x;
  const int p_local = tid >> 2, quad = tid & 3;
  const int grow = doc*PP + pb + p_local;
  const int he = hts[grow*2+0], te = hts[grow*2+1];
  const u16* ha = ent_att_bf + ((size_t)(doc*EE + he)*HH)*CL;
  const u16* ta = ent_att_bf + ((size_t)(doc*EE + te)*HH)*CL;
  const int jj = j0 + quad*16;

  float acc[16] = {};
  #pragma unroll
  for (int h=0; h<HH; h++){
    const uint4* pa = (const uint4*)(ha + h*CL + jj);
    const uint4* pb4 = (const uint4*)(ta + h*CL + jj);
    uint4 a0 = pa[0], a1 = pa[1];
    uint4 b0 = pb4[0], b1 = pb4[1];
    unsigned ua[8] = {a0.x,a0.y,a0.z,a0.w,a1.x,a1.y,a1.z,a1.w};
    unsigned ub[8] = {b0.x,b0.y,b0.z,b0.w,b1.x,b1.y,b1.z,b1.w};
    #pragma unroll
    for (int q=0;q<8;q++){
      acc[2*q]   += bf16u_to_f(ua[q]&0xffffu) * bf16u_to_f(ub[q]&0xffffu);
      acc[2*q+1] += bf16u_to_f(ua[q]>>16)     * bf16u_to_f(ub[q]>>16);
    }
  }
  float sum = 0.f;
  unsigned o[8];
  #pragma unroll
  for (int q=0;q<8;q++){
    float v0 = acc[2*q]   * (1.f/HH);
    float v1 = acc[2*q+1] * (1.f/HH);
    sum += v0 + v1;
    o[q] = f_to_bf16u(v0) | (f_to_bf16u(v1)<<16);
  }
  uint4* dst = (uint4*)(u_ht_bf + (size_t)grow*CL + jj);
  dst[0] = make_uint4(o[0],o[1],o[2],o[3]);
  dst[1] = make_uint4(o[4],o[5],o[6],o[7]);
  sum += __shfl_xor(sum, 1, 64);
  sum += __shfl_xor(sum, 2, 64);
  if (quad == 0) atomicAdd(&S[grow], sum);
}

// ---------------------------------------------------------------
// 4. rs_bf = bf16( (1/S_row) * (u_ht @ seq) ) via MFMA.
//    BM=64 BN=64 BK=64; grid (4,12,4) = 192 blocks.
// ---------------------------------------------------------------
__global__ __launch_bounds__(256) void k_gemm_rs_mfma(
    const u16* __restrict__ u_ht_bf, const u16* __restrict__ seq_t_bf,
    const float* __restrict__ S, u16* __restrict__ rs_bf)
{
  const int rt = blockIdx.x, ct = blockIdx.y, doc = blockIdx.z;
  const u16* A  = u_ht_bf + (size_t)doc*PP*CL;
  const u16* Bt = seq_t_bf + (size_t)doc*DD*CL;
  const int row0 = rt*64, col0 = ct*64;
  __shared__ __align__(16) u16 As[64*64];
  __shared__ __align__(16) u16 Bs[64*64];
  const int tid = threadIdx.x, lane = tid & 63, wave = tid >> 6;
  const int m = lane & 15, j8 = lane >> 4;
  const int srow8 = lane >> 3, sc8 = lane & 7;
  f32x4 acc[4];
  #pragma unroll
  for (int b=0;b<4;b++) acc[b] = (f32x4){0.f,0.f,0.f,0.f};

  for (int k0 = 0; k0 < CL; k0 += 64){
    __syncthreads();
    #pragma unroll
    for (int ii=0; ii<2; ii++){
      int row = ii*32 + wave*8 + srow8;
      int gc = sc8 ^ (row & 7);
      const u16* gpA = A + (size_t)(row0+row)*CL + k0 + gc*8;
      GLOAD_LDS16(gpA, &As[(ii*32 + wave*8)*64]);
      const u16* gpB = Bt + (size_t)(col0+row)*CL + k0 + gc*8;
      GLOAD_LDS16(gpB, &Bs[(ii*32 + wave*8)*64]);
    }
    __syncthreads();
    #pragma unroll
    for (int h=0; h<2; h++){
      short8 af, bf[4];
      {
        int r = wave*16 + m;
        int c = (h*4 + j8) ^ (r & 7);
        af = *(const short8*)&As[r*64 + c*8];
      }
      #pragma unroll
      for (int nt=0; nt<4; nt++){
        int n = nt*16 + m;
        int c = (h*4 + j8) ^ (n & 7);
        bf[nt] = *(const short8*)&Bs[n*64 + c*8];
      }
      #pragma unroll
      for (int nt=0; nt<4; nt++)
        acc[nt] = __builtin_amdgcn_mfma_f32_16x16x32_bf16(af, bf[nt], acc[nt], 0,0,0);
    }
  }

  // hoisted 1/S scales (independent of nt)
  float sc[4];
  #pragma unroll
  for (int reg=0; reg<4; reg++){
    int rowg = doc*PP + row0 + wave*16 + j8*4 + reg;
    sc[reg] = 1.f / (S[rowg] + 1e-30f);
  }
  #pragma unroll
  for (int nt=0; nt<4; nt++){
    int colg = col0 + nt*16 + m;
    #pragma unroll
    for (int reg=0; reg<4; reg++){
      int rowg = doc*PP + row0 + wave*16 + j8*4 + reg;
      rs_bf[(size_t)rowg*DD + colg] = (u16)f_to_bf16u(acc[nt][reg] * sc[reg]);
    }
  }
}

// ---------------------------------------------------------------
// 5. hs2h = f16(tanh([ent_emb|rs] @ W_head + b_head)); ts2h analogous.
//    BM=64 BN=64 BK=64; grid (16,12,2) = 384 blocks (was 192 @ BM=128).
//    Same per-output MFMA sequence -> bit-identical result.
// ---------------------------------------------------------------
__global__ __launch_bounds__(256) void k_gemm_ht_mfma(
    const u16* __restrict__ ent_emb_bf, const u16* __restrict__ rs_bf,
    const int* __restrict__ hts,
    const u16* __restrict__ Wht, const u16* __restrict__ Wtt,
    const float* __restrict__ b_head, const float* __restrict__ b_tail,
    u16* __restrict__ hs2h, u16* __restrict__ ts2h)
{
  const int rt = blockIdx.x, ct = blockIdx.y, z = blockIdx.z;
  const u16* Bt   = z ? Wtt : Wht;
  const float* bias = z ? b_tail : b_head;
  u16* C          = z ? ts2h : hs2h;
  const int row0 = rt*64, col0 = ct*64;
  __shared__ __align__(16) u16 As[64*64];
  __shared__ __align__(16) u16 Bs[64*64];
  const int tid = threadIdx.x, lane = tid & 63, wave = tid >> 6;
  const int m = lane & 15, j8 = lane >> 4;
  const int srow8 = lane >> 3, sc8 = lane & 7;

  const u16* gEnt[2]; const u16* gRs[2]; int gcA[2];
  #pragma unroll
  for (int ii=0; ii<2; ii++){
    int row  = ii*32 + wave*8 + srow8;
    int grow = row0 + row;
    int ent  = hts[grow*2 + z];
    gEnt[ii] = ent_emb_bf + ((size_t)((grow>>8)*EE + ent))*DD;
    gRs[ii]  = rs_bf + (size_t)grow*DD;
    gcA[ii]  = (sc8 ^ (row & 7)) * 8;
  }

  f32x4 acc[4];
  #pragma unroll
  for (int b=0;b<4;b++) acc[b] = (f32x4){0.f,0.f,0.f,0.f};

  for (int k0 = 0; k0 < 1536; k0 += 64){
    __syncthreads();
    #pragma unroll
    for (int ii=0; ii<2; ii++){
      const u16* gpA = (k0 < DD) ? (gEnt[ii] + k0 + gcA[ii])
                                 : (gRs[ii] + (k0-DD) + gcA[ii]);
      GLOAD_LDS16(gpA, &As[(ii*32 + wave*8)*64]);
      int row = ii*32 + wave*8 + srow8;
      int gc = sc8 ^ (row & 7);
      const u16* gpB = Bt + (size_t)(col0+row)*1536 + k0 + gc*8;
      GLOAD_LDS16(gpB, &Bs[(ii*32 + wave*8)*64]);
    }
    __syncthreads();
    #pragma unroll
    for (int h=0; h<2; h++){
      short8 af, bf[4];
      {
        int r = wave*16 + m;
        int c = (h*4 + j8) ^ (r & 7);
        af = *(const short8*)&As[r*64 + c*8];
      }
      #pragma unroll
      for (int nt=0; nt<4; nt++){
        int n = nt*16 + m;
        int c = (h*4 + j8) ^ (n & 7);
        bf[nt] = *(const short8*)&Bs[n*64 + c*8];
      }
      #pragma unroll
      for (int nt=0; nt<4; nt++)
        acc[nt] = __builtin_amdgcn_mfma_f32_16x16x32_bf16(af, bf[nt], acc[nt], 0,0,0);
    }
  }

  #pragma unroll
  for (int nt=0; nt<4; nt++){
    int colg = col0 + nt*16 + m;
    float bv = bias[colg];
    #pragma unroll
    for (int reg=0; reg<4; reg++){
      int rowg = row0 + wave*16 + j8*4 + reg;
      C[(size_t)rowg*DD + colg] = f_to_f16u(tanhf(acc[nt][reg] + bv));
    }
  }
}

// ---------------------------------------------------------------
// 7. bilinear via f16 MFMA 16x16x32; A-frag = pk_mul(b1 splat, b2).
//    BM=64: grid (16,48) = 768 blocks (3 full CU rounds).
//    4-deep Ws staging (16 barriers/block). pbuf epilogue (no atomics --
//    R3 measured atomics at +22 us from 48-way line contention).
// ---------------------------------------------------------------
__global__ __launch_bounds__(256) void k_bilinear(
    const u16* __restrict__ hs2h, const u16* __restrict__ ts2h,
    const u16* __restrict__ Wt2, float* __restrict__ pbuf)
{
  const int rt = blockIdx.x;          // 0..15  (64 rows each)
  const int sp = blockIdx.y;          // 0..47  (K range [sp*1024, +1024))
  const int kb = sp >> 2;             // 0..11
  const int i0 = (sp & 3) * 16;       // i base within this kb
  const int row0 = rt * 64;

  __shared__ __align__(16) u16 b1s[64][24];    // 3072 B
  __shared__ __align__(16) u16 b2s[64][72];    // 9216 B
  __shared__ __align__(16) u16 Ws[4][4480];    // 35840 B (4 c-tiles)

  const int tid = threadIdx.x;
  const int lane = tid & 63, wave = tid >> 6;
  const int m = lane & 15, j8 = lane >> 4;

  // stage b1 (16 f16/row): 64 rows -> 128 uint4
  if (tid < 128){
    int r = tid >> 1, half = tid & 1;
    uint4 v = *(const uint4*)&hs2h[(size_t)(row0+r)*EMBD + kb*64 + i0 + half*8];
    *(uint4*)&b1s[r][half*8] = v;
  }
  // stage b2 (64 f16/row): 64 rows -> 512 uint4
  #pragma unroll
  for (int q=0;q<2;q++){
    int u = tid + q*256;
    int r = u >> 3, seg = u & 7;
    uint4 v = *(const uint4*)&ts2h[(size_t)(row0+r)*EMBD + kb*64 + seg*8];
    *(uint4*)&b2s[r][seg*8] = v;
  }

  const uint4* gsrc = (const uint4*)(Wt2 + (size_t)(sp*32)*4480);
  uint4* ws4 = (uint4*)Ws;
  // prefetch super 0: 2240 uint4 (4 c-tiles of 560)
  uint4 pf0,pf1,pf2,pf3,pf4,pf5,pf6,pf7,pf8;
  pf0 = gsrc[tid];        pf1 = gsrc[tid+256];  pf2 = gsrc[tid+512];
  pf3 = gsrc[tid+768];    pf4 = gsrc[tid+1024]; pf5 = gsrc[tid+1280];
  pf6 = gsrc[tid+1536];   pf7 = gsrc[tid+1792];
  if (tid < 192) pf8 = gsrc[tid+2048];

  f32x4 acc[7];
  #pragma unroll
  for (int nt=0;nt<7;nt++) acc[nt] = (f32x4){0.f,0.f,0.f,0.f};

  for (int s=0; s<8; s++){
    __syncthreads();
    ws4[tid]      = pf0; ws4[tid+256]  = pf1; ws4[tid+512]  = pf2;
    ws4[tid+768]  = pf3; ws4[tid+1024] = pf4; ws4[tid+1280] = pf5;
    ws4[tid+1536] = pf6; ws4[tid+1792] = pf7;
    if (tid < 192) ws4[tid+2048] = pf8;
    if (s+1 < 8){
      size_t b = (size_t)(s+1)*2240;
      pf0 = gsrc[b+tid];      pf1 = gsrc[b+tid+256];  pf2 = gsrc[b+tid+512];
      pf3 = gsrc[b+tid+768];  pf4 = gsrc[b+tid+1024]; pf5 = gsrc[b+tid+1280];
      pf6 = gsrc[b+tid+1536]; pf7 = gsrc[b+tid+1792];
      if (tid < 192) pf8 = gsrc[b+tid+2048];
    }
    __syncthreads();

    #pragma unroll
    for (int qq=0; qq<4; qq++){
      const int c = s*4 + qq;          // 0..31
      const int i_rel = c >> 1;        // 0..15
      const int j0 = (c & 1) * 32;

      half8 bfr[7];
      #pragma unroll
      for (int nt=0;nt<7;nt++)
        bfr[nt] = *(const half8*)&Ws[qq][(nt*16 + m)*40 + j8*8];

      int r = wave*16 + m;
      _Float16 sv1 = *(const _Float16*)&b1s[r][i_rel];
      half8 sv = {sv1,sv1,sv1,sv1,sv1,sv1,sv1,sv1};
      half8 b2v = *(const half8*)&b2s[r][j0 + j8*8];
      half8 af = sv * b2v;             // v_pk_mul_f16 x4
      #pragma unroll
      for (int nt=0;nt<7;nt++)
        acc[nt] = __builtin_amdgcn_mfma_f32_16x16x32_f16(af, bfr[nt], acc[nt], 0, 0, 0);
    }
  }

  // epilogue: plain stores to partial buffer (no atomics)
  float* dst = pbuf + ((size_t)sp*RTOT + row0)*112;
  #pragma unroll
  for (int nt=0;nt<7;nt++){
    int col = nt*16 + m;
    #pragma unroll
    for (int reg=0;reg<4;reg++){
      int lrow = wave*16 + j8*4 + reg;
      dst[(size_t)lrow*112 + col] = acc[nt][reg];
    }
  }
}

// ---------------------------------------------------------------
// 8. reduce partials + bias -> logits
// ---------------------------------------------------------------
__global__ __launch_bounds__(256) void k_reduce_logits(
    const float* __restrict__ pbuf, const float* __restrict__ b_bil,
    float* __restrict__ logits)
{
  int idx = blockIdx.x*256 + threadIdx.x;   // over RTOT*112
  if (idx >= RTOT*112) return;
  int col = idx % 112, row = idx / 112;
  if (col >= OUTD) return;
  float s0 = 0.f, s1 = 0.f, s2 = 0.f, s3 = 0.f;
  const size_t stride = (size_t)RTOT*112;
  #pragma unroll
  for (int sp=0; sp<NSPLIT; sp+=4){
    s0 += pbuf[(sp+0)*stride + idx];
    s1 += pbuf[(sp+1)*stride + idx];
    s2 += pbuf[(sp+2)*stride + idx];
    s3 += pbuf[(sp+3)*stride + idx];
  }
  logits[(size_t)row*OUTD + col] = (s0+s1) + (s2+s3) + b_bil[col];
}

// ---------------------------------------------------------------
extern "C" void kernel_launch(void* const* d_in, const int* in_sizes, int n_in,
                              void* d_out, int out_size, void* d_ws, size_t ws_size,
                              hipStream_t stream)
{
  const float* seq    = (const float*)d_in[0];
  const float* attn   = (const float*)d_in[1];
  const int*   mpos   = (const int*)d_in[2];
  const int*   hts    = (const int*)d_in[3];
  const float* W_head = (const float*)d_in[4];
  const float* b_head = (const float*)d_in[5];
  const float* W_tail = (const float*)d_in[6];
  const float* b_tail = (const float*)d_in[7];
  const float* W_bil  = (const float*)d_in[8];
  const float* b_bil  = (const float*)d_in[9];
  float* logits = (float*)d_out;

  float* ws = (float*)d_ws;
  u16*   ent_emb_bf = (u16*)(ws + 0);          //  98304 u16 ->  49152 f
  float* S          = ws + 49152;              //   1024 f
  u16*   rs_bf      = (u16*)(ws + 50176);      // 786432 u16 -> 393216 f
  u16*   hs2h       = (u16*)(ws + 443392);     // 786432 u16 -> 393216 f
  u16*   ts2h       = (u16*)(ws + 836608);     // 786432 u16 -> 393216 f
  u16*   Wh_t       = (u16*)(ws + 1229824);    // 1179648 u16 -> 589824 f
  u16*   Wt_t       = (u16*)(ws + 1819648);    // 1179648 u16 -> 589824 f
  u16*   ent_att_bf = (u16*)(ws + 2409472);    // 1572864 u16 -> 786432 f
  u16*   u_ht_bf    = (u16*)(ws + 3195904);    // 1048576 u16 -> 524288 f
  u16*   seq_t_bf   = (u16*)(ws + 3720192);    // 3145728 u16 -> 1572864 f
  u16*   Wt2        = (u16*)(ws + 5293056);    // 6881280 u16 -> 3440640 f
  float* pbuf       = ws + 8733696;            // 5505024 f (NSPLIT=48)

  // one fused launch for all independent preprocessing
  k_preproc<<<8064, 256, 0, stream>>>(seq, attn, mpos, W_head, W_tail, W_bil,
      ent_emb_bf, ent_att_bf, seq_t_bf, Wh_t, Wt_t, Wt2, S);
  k_ht_att<<<dim3(16, 4, 4), 256, 0, stream>>>(ent_att_bf, hts, u_ht_bf, S);
  k_gemm_rs_mfma<<<dim3(4, 12, 4), 256, 0, stream>>>(u_ht_bf, seq_t_bf, S, rs_bf);
  k_gemm_ht_mfma<<<dim3(16, 12, 2), 256, 0, stream>>>(ent_emb_bf, rs_bf, hts,
      Wh_t, Wt_t, b_head, b_tail, hs2h, ts2h);
  k_bilinear<<<dim3(RTOT/64, NSPLIT), 256, 0, stream>>>(hs2h, ts2h, Wt2, pbuf);
  k_reduce_logits<<<(RTOT*112+255)/256, 256, 0, stream>>>(pbuf, b_bil, logits);
}